// Round 2
// baseline (429.874 us; speedup 1.0000x reference)
//
#include <hip/hip_runtime.h>
#include <hip/hip_bf16.h>

#define N_NODES 10000
#define N_EDGES 160000
#define TE 32   // edges per block

typedef __attribute__((ext_vector_type(8))) short bfrag_t;   // 8 x bf16
typedef __attribute__((ext_vector_type(4))) float facc_t;    // 4 x f32

__device__ inline short f2bf(float f) {
    union { float f; unsigned u; } x; x.f = f;
    unsigned r = x.u + 0x7FFFu + ((x.u >> 16) & 1u);
    return (short)(r >> 16);
}

// Pack W2 (256x1024 f32, row-major) into MFMA B fragments, bf16, with 1/16 scale folded.
// frag f = ((p*16 + nt)*8 + k); bf16 element offset = f*512 + lane*8 + j
// value = W2[k*32 + (lane>>4)*8 + j][p*256 + nt*16 + (lane&15)] / 16
__global__ void pack_w2(const float* __restrict__ w2, short* __restrict__ outp) {
    int g = blockIdx.x * blockDim.x + threadIdx.x;  // 0..262143
    int j    = g & 7;
    int lane = (g >> 3) & 63;
    int k    = (g >> 9) & 7;
    int nt   = (g >> 12) & 15;
    int p    = g >> 16;
    int row = k * 32 + ((lane >> 4) << 3) + j;
    int col = p * 256 + nt * 16 + (lane & 15);
    outp[g] = f2bf(w2[row * 1024 + col] * 0.0625f);
}

__global__ __launch_bounds__(256) void conv_kernel(
    const int* __restrict__ esrc, const int* __restrict__ edst,
    const float* __restrict__ nodef, const float* __restrict__ esh,
    const float* __restrict__ ell, const float* __restrict__ w1,
    const short* __restrict__ w2p, const int* __restrict__ nn,
    float* __restrict__ outg)
{
    __shared__ __align__(16) short h_lds[TE * 256];   // bf16, swizzled rows of 512B
    __shared__ __align__(16) float x_lds[TE][68];     // node_features[src], padded
    __shared__ float a0_lds[TE][17];   // s0*y0
    __shared__ float a1_lds[TE][17];   // sum_i v1[u][i]*y1[i]
    __shared__ float r0_lds[TE][17];   // path0 partial
    __shared__ float r1_lds[TE][17];   // path1 partial
    __shared__ float r2_lds[TE][17];   // path2 b[v]
    __shared__ float r3_lds[TE][49];   // path3 c[v*3+i]
    __shared__ float sh_lds[TE][4];
    __shared__ float el_lds[TE][3];
    __shared__ int   src_lds[TE];
    __shared__ int   dst_lds[TE];

    const int tid = threadIdx.x;
    const int e0  = blockIdx.x * TE;

    // ---- phase A: small edge-wise loads ----
    if (tid < TE)           src_lds[tid]       = esrc[e0 + tid];
    else if (tid < 2 * TE)  dst_lds[tid - TE]  = edst[e0 + tid - TE];
    if (tid < 4 * TE) {
        sh_lds[tid >> 2][tid & 3] = esh[e0 * 4 + tid];
    } else if (tid < 7 * TE) {
        int q = tid - 4 * TE;
        el_lds[q / 3][q % 3] = ell[e0 * 3 + q];
    }
    __syncthreads();

    // ---- phase B: x gather, h compute (to LDS bf16), coefficient precompute ----
    {
        int e = tid >> 3, part = tid & 7;
        int s = src_lds[e];
        const float4* sp = (const float4*)(nodef + (size_t)s * 64 + part * 8);
        float4 u0 = sp[0], u1 = sp[1];
        float* xr = &x_lds[e][part * 8];
        *(float4*)(xr)     = u0;
        *(float4*)(xr + 4) = u1;
    }
    {
        int e = tid >> 3, c0 = (tid & 7) * 32;
        float l0 = el_lds[e][0], l1 = el_lds[e][1], l2 = el_lds[e][2];
        #pragma unroll
        for (int s = 0; s < 4; ++s) {
            bfrag_t hv;
            #pragma unroll
            for (int m = 0; m < 8; ++m) {
                int c = c0 + s * 8 + m;
                float a = l0 * w1[c] + l1 * w1[256 + c] + l2 * w1[512 + c];
                a = fmaxf(a, 0.f) * 0.8164965809277260f;  // sqrt(2/3), relu scale folded
                hv[m] = f2bf(a);
            }
            // XOR swizzle applied to the FULL byte address (must match read side)
            int byte = (e * 512 + (c0 + s * 8) * 2) ^ ((e & 7) << 4);
            *(bfrag_t*)((char*)h_lds + byte) = hv;
        }
    }
    __syncthreads();
    {
        #pragma unroll
        for (int q = tid; q < TE * 16; q += 256) {
            int e = q >> 4, u = q & 15;
            float y0 = sh_lds[e][0];
            a0_lds[e][u] = x_lds[e][u] * y0;
            a1_lds[e][u] = x_lds[e][16 + u * 3 + 0] * sh_lds[e][1]
                         + x_lds[e][16 + u * 3 + 1] * sh_lds[e][2]
                         + x_lds[e][16 + u * 3 + 2] * sh_lds[e][3];
        }
    }
    __syncthreads();

    // ---- phase C: MFMA GEMM (wave p == TP path p) fused with TP reduction ----
    const int lane = tid & 63;
    const int p    = tid >> 6;
    const int g    = lane >> 4;
    const int v    = lane & 15;

    float acc0[2][4];     // paths 0..2: partial sums per (mt, r)
    float acc3[2][4][3];  // path 3: per i
    #pragma unroll
    for (int mt = 0; mt < 2; ++mt)
        #pragma unroll
        for (int r = 0; r < 4; ++r) {
            acc0[mt][r] = 0.f;
            acc3[mt][r][0] = 0.f; acc3[mt][r][1] = 0.f; acc3[mt][r][2] = 0.f;
        }

    const bfrag_t* Bp = (const bfrag_t*)w2p + (size_t)(p * 128) * 64 + lane;

    // per-row base byte offsets and swizzles (XOR applied AFTER adding koff)
    const int rb0  = v * 512;          // mt=0 row base
    const int rb1  = (16 + v) * 512;   // mt=1 row base
    const int swz  = (v & 7) << 4;     // same for v and 16+v

    #pragma unroll
    for (int ntc = 0; ntc < 4; ++ntc) {
        facc_t acc[2][4];
        #pragma unroll
        for (int mt = 0; mt < 2; ++mt)
            #pragma unroll
            for (int q = 0; q < 4; ++q)
                acc[mt][q] = (facc_t){0.f, 0.f, 0.f, 0.f};

        #pragma unroll
        for (int k = 0; k < 8; ++k) {
            int koff = (k * 32 + 8 * g) * 2;   // multiple of 16 bytes
            bfrag_t a0 = *(const bfrag_t*)((const char*)h_lds + ((rb0 + koff) ^ swz));
            bfrag_t a1 = *(const bfrag_t*)((const char*)h_lds + ((rb1 + koff) ^ swz));
            #pragma unroll
            for (int q = 0; q < 4; ++q) {
                int nt = ntc * 4 + q;
                bfrag_t b = Bp[(size_t)(nt * 8 + k) * 64];
                acc[0][q] = __builtin_amdgcn_mfma_f32_16x16x32_bf16(a0, b, acc[0][q], 0, 0, 0);
                acc[1][q] = __builtin_amdgcn_mfma_f32_16x16x32_bf16(a1, b, acc[1][q], 0, 0, 0);
            }
        }
        // partial TP reduction over u = nt for this chunk
        #pragma unroll
        for (int mt = 0; mt < 2; ++mt)
            #pragma unroll
            for (int r = 0; r < 4; ++r) {
                int e = mt * 16 + 4 * g + r;
                #pragma unroll
                for (int q = 0; q < 4; ++q) {
                    int u = ntc * 4 + q;
                    float wv = acc[mt][q][r];
                    if (p == 0)       acc0[mt][r] += a0_lds[e][u] * wv;
                    else if (p == 1)  acc0[mt][r] += a1_lds[e][u] * wv;
                    else if (p == 2)  acc0[mt][r] += x_lds[e][u] * wv;
                    else {
                        acc3[mt][r][0] += x_lds[e][16 + u * 3 + 0] * wv;
                        acc3[mt][r][1] += x_lds[e][16 + u * 3 + 1] * wv;
                        acc3[mt][r][2] += x_lds[e][16 + u * 3 + 2] * wv;
                    }
                }
            }
    }

    #pragma unroll
    for (int mt = 0; mt < 2; ++mt)
        #pragma unroll
        for (int r = 0; r < 4; ++r) {
            int e = mt * 16 + 4 * g + r;
            if (p == 0)       r0_lds[e][v] = acc0[mt][r];
            else if (p == 1)  r1_lds[e][v] = acc0[mt][r];
            else if (p == 2)  r2_lds[e][v] = acc0[mt][r];
            else {
                r3_lds[e][v * 3 + 0] = acc3[mt][r][0];
                r3_lds[e][v * 3 + 1] = acc3[mt][r][1];
                r3_lds[e][v * 3 + 2] = acc3[mt][r][2];
            }
        }
    __syncthreads();

    // ---- phase D: combine + scatter-add ----
    {
        float scale = rsqrtf((float)nn[0]);
        const float pw0 = 0.17677669529663687f;          // sqrt(1/32); note pw1/sqrt(3) == pw0
        float k0 = pw0 * scale;
        float k1 = k0 * 0.57735026918962576f;            // extra 1/sqrt(3) on path 1

        int e  = tid >> 3;
        int j0 = (tid & 7) * 8;
        int d  = dst_lds[e];
        float y0  = sh_lds[e][0];
        float y1x = sh_lds[e][1], y1y = sh_lds[e][2], y1z = sh_lds[e][3];
        float* op = outg + (size_t)d * 64;
        #pragma unroll
        for (int jj = 0; jj < 8; ++jj) {
            int j = j0 + jj;
            float val;
            if (j < 16) {
                val = k0 * r0_lds[e][j] + k1 * r1_lds[e][j];
            } else {
                int t2 = j - 16;
                int vv = t2 / 3;
                int i  = t2 - vv * 3;
                float y1i = (i == 0) ? y1x : ((i == 1) ? y1y : y1z);
                val = k0 * (y1i * r2_lds[e][vv] + y0 * r3_lds[e][t2]);
            }
            atomicAdd(op + j, val);
        }
    }
}

extern "C" void kernel_launch(void* const* d_in, const int* in_sizes, int n_in,
                              void* d_out, int out_size, void* d_ws, size_t ws_size,
                              hipStream_t stream) {
    const int*   esrc  = (const int*)d_in[0];
    const int*   edst  = (const int*)d_in[1];
    const float* nodef = (const float*)d_in[2];
    const float* esh   = (const float*)d_in[3];
    const float* ellv  = (const float*)d_in[4];
    const float* w1    = (const float*)d_in[5];
    const float* w2    = (const float*)d_in[6];
    const int*   nn    = (const int*)d_in[7];
    float* outg = (float*)d_out;
    short* w2p  = (short*)d_ws;   // 512 KiB packed bf16 W2 fragments

    hipMemsetAsync(d_out, 0, (size_t)out_size * sizeof(float), stream);
    pack_w2<<<1024, 256, 0, stream>>>(w2, w2p);
    conv_kernel<<<N_EDGES / TE, 256, 0, stream>>>(esrc, edst, nodef, esh, ellv, w1, w2p, nn, outg);
}

// Round 3
// 343.502 us; speedup vs baseline: 1.2514x; 1.2514x over previous
//
#include <hip/hip_runtime.h>
#include <hip/hip_bf16.h>

#define N_NODES 10000
#define N_EDGES 160000
#define TE 32   // edges per block

typedef __attribute__((ext_vector_type(8))) short bfrag_t;   // 8 x bf16
typedef __attribute__((ext_vector_type(4))) float facc_t;    // 4 x f32

__device__ inline short f2bf(float f) {
    union { float f; unsigned u; } x; x.f = f;
    unsigned r = x.u + 0x7FFFu + ((x.u >> 16) & 1u);
    return (short)(r >> 16);
}

// Pack W2 (256x1024 f32, row-major) into MFMA B fragments, bf16, with 1/16 scale folded.
__global__ void pack_w2(const float* __restrict__ w2, short* __restrict__ outp) {
    int g = blockIdx.x * blockDim.x + threadIdx.x;  // 0..262143
    int j    = g & 7;
    int lane = (g >> 3) & 63;
    int k    = (g >> 9) & 7;
    int nt   = (g >> 12) & 15;
    int p    = g >> 16;
    int row = k * 32 + ((lane >> 4) << 3) + j;
    int col = p * 256 + nt * 16 + (lane & 15);
    outp[g] = f2bf(w2[row * 1024 + col] * 0.0625f);
}

// ---- dst-sort infrastructure ----
__global__ void zero_counts(int* __restrict__ counts) {
    int i = blockIdx.x * blockDim.x + threadIdx.x;
    if (i < N_NODES) counts[i] = 0;
}

__global__ void hist_kernel(const int* __restrict__ edst, int* __restrict__ counts) {
    int e = blockIdx.x * blockDim.x + threadIdx.x;
    if (e < N_EDGES) atomicAdd(&counts[edst[e]], 1);
}

// single-block exclusive scan of counts[10000] -> cursor[]
__global__ __launch_bounds__(256) void scan_kernel(const int* __restrict__ counts,
                                                   int* __restrict__ cursor) {
    __shared__ int part[256];
    const int t = threadIdx.x;
    const int CH = 40;                      // 256*40 = 10240 >= 10000
    int base = t * CH;
    int s = 0;
    for (int i = 0; i < CH; ++i) {
        int idx = base + i;
        if (idx < N_NODES) s += counts[idx];
    }
    part[t] = s;
    __syncthreads();
    // Hillis-Steele inclusive scan (read-sync-write-sync)
    for (int off = 1; off < 256; off <<= 1) {
        int add = (t >= off) ? part[t - off] : 0;
        __syncthreads();
        part[t] += add;
        __syncthreads();
    }
    int run = part[t] - s;                  // exclusive prefix of this chunk
    for (int i = 0; i < CH; ++i) {
        int idx = base + i;
        if (idx < N_NODES) {
            cursor[idx] = run;
            run += counts[idx];
        }
    }
}

__global__ void scatter_kernel(const int* __restrict__ edst, int* __restrict__ cursor,
                               int* __restrict__ perm) {
    int e = blockIdx.x * blockDim.x + threadIdx.x;
    if (e < N_EDGES) {
        int pos = atomicAdd(&cursor[edst[e]], 1);
        perm[pos] = e;
    }
}

__global__ __launch_bounds__(256) void conv_kernel(
    const int* __restrict__ perm,
    const int* __restrict__ esrc, const int* __restrict__ edst,
    const float* __restrict__ nodef, const float* __restrict__ esh,
    const float* __restrict__ ell, const float* __restrict__ w1,
    const short* __restrict__ w2p, const int* __restrict__ nn,
    float* __restrict__ outg)
{
    __shared__ __align__(16) short h_lds[TE * 256];   // bf16, swizzled rows of 512B (aliased as vbuf in phase D)
    __shared__ __align__(16) float x_lds[TE][68];     // node_features[src], padded
    __shared__ float a0_lds[TE][17];   // s0*y0
    __shared__ float a1_lds[TE][17];   // sum_i v1[u][i]*y1[i]
    __shared__ float r0_lds[TE][17];   // path0 partial
    __shared__ float r1_lds[TE][17];   // path1 partial
    __shared__ float r2_lds[TE][17];   // path2 b[v]
    __shared__ float r3_lds[TE][49];   // path3 c[v*3+i]
    __shared__ float sh_lds[TE][4];
    __shared__ float el_lds[TE][3];
    __shared__ int   src_lds[TE];
    __shared__ int   dst_lds[TE];
    __shared__ int   head_lds[TE];

    const int tid = threadIdx.x;
    const int e0  = blockIdx.x * TE;

    // ---- phase A: gathered edge-wise loads (via perm) ----
    if (tid < TE) {
        int pe = perm[e0 + tid];
        src_lds[tid] = esrc[pe];
        dst_lds[tid] = edst[pe];
        float4 s4 = *(const float4*)(esh + (size_t)pe * 4);
        sh_lds[tid][0] = s4.x; sh_lds[tid][1] = s4.y;
        sh_lds[tid][2] = s4.z; sh_lds[tid][3] = s4.w;
        const float* lp = ell + (size_t)pe * 3;
        el_lds[tid][0] = lp[0]; el_lds[tid][1] = lp[1]; el_lds[tid][2] = lp[2];
    }
    __syncthreads();

    // ---- phase B: x gather, h compute (to LDS bf16), coefficient precompute ----
    {
        int e = tid >> 3, part = tid & 7;
        int s = src_lds[e];
        const float4* sp = (const float4*)(nodef + (size_t)s * 64 + part * 8);
        float4 u0 = sp[0], u1 = sp[1];
        float* xr = &x_lds[e][part * 8];
        *(float4*)(xr)     = u0;
        *(float4*)(xr + 4) = u1;
    }
    {
        int e = tid >> 3, c0 = (tid & 7) * 32;
        float l0 = el_lds[e][0], l1 = el_lds[e][1], l2 = el_lds[e][2];
        #pragma unroll
        for (int s = 0; s < 4; ++s) {
            bfrag_t hv;
            #pragma unroll
            for (int m = 0; m < 8; ++m) {
                int c = c0 + s * 8 + m;
                float a = l0 * w1[c] + l1 * w1[256 + c] + l2 * w1[512 + c];
                a = fmaxf(a, 0.f) * 0.8164965809277260f;  // sqrt(2/3), relu scale folded
                hv[m] = f2bf(a);
            }
            int byte = (e * 512 + (c0 + s * 8) * 2) ^ ((e & 7) << 4);
            *(bfrag_t*)((char*)h_lds + byte) = hv;
        }
    }
    __syncthreads();
    {
        #pragma unroll
        for (int q = tid; q < TE * 16; q += 256) {
            int e = q >> 4, u = q & 15;
            float y0 = sh_lds[e][0];
            a0_lds[e][u] = x_lds[e][u] * y0;
            a1_lds[e][u] = x_lds[e][16 + u * 3 + 0] * sh_lds[e][1]
                         + x_lds[e][16 + u * 3 + 1] * sh_lds[e][2]
                         + x_lds[e][16 + u * 3 + 2] * sh_lds[e][3];
        }
    }
    __syncthreads();

    // ---- phase C: MFMA GEMM (wave p == TP path p) fused with TP reduction ----
    const int lane = tid & 63;
    const int p    = tid >> 6;
    const int g    = lane >> 4;
    const int v    = lane & 15;

    float acc0[2][4];
    float acc3[2][4][3];
    #pragma unroll
    for (int mt = 0; mt < 2; ++mt)
        #pragma unroll
        for (int r = 0; r < 4; ++r) {
            acc0[mt][r] = 0.f;
            acc3[mt][r][0] = 0.f; acc3[mt][r][1] = 0.f; acc3[mt][r][2] = 0.f;
        }

    const bfrag_t* Bp = (const bfrag_t*)w2p + (size_t)(p * 128) * 64 + lane;

    const int rb0  = v * 512;
    const int rb1  = (16 + v) * 512;
    const int swz  = (v & 7) << 4;

    #pragma unroll
    for (int ntc = 0; ntc < 4; ++ntc) {
        facc_t acc[2][4];
        #pragma unroll
        for (int mt = 0; mt < 2; ++mt)
            #pragma unroll
            for (int q = 0; q < 4; ++q)
                acc[mt][q] = (facc_t){0.f, 0.f, 0.f, 0.f};

        #pragma unroll
        for (int k = 0; k < 8; ++k) {
            int koff = (k * 32 + 8 * g) * 2;
            bfrag_t a0 = *(const bfrag_t*)((const char*)h_lds + ((rb0 + koff) ^ swz));
            bfrag_t a1 = *(const bfrag_t*)((const char*)h_lds + ((rb1 + koff) ^ swz));
            #pragma unroll
            for (int q = 0; q < 4; ++q) {
                int nt = ntc * 4 + q;
                bfrag_t b = Bp[(size_t)(nt * 8 + k) * 64];
                acc[0][q] = __builtin_amdgcn_mfma_f32_16x16x32_bf16(a0, b, acc[0][q], 0, 0, 0);
                acc[1][q] = __builtin_amdgcn_mfma_f32_16x16x32_bf16(a1, b, acc[1][q], 0, 0, 0);
            }
        }
        #pragma unroll
        for (int mt = 0; mt < 2; ++mt)
            #pragma unroll
            for (int r = 0; r < 4; ++r) {
                int e = mt * 16 + 4 * g + r;
                #pragma unroll
                for (int q = 0; q < 4; ++q) {
                    int u = ntc * 4 + q;
                    float wv = acc[mt][q][r];
                    if (p == 0)       acc0[mt][r] += a0_lds[e][u] * wv;
                    else if (p == 1)  acc0[mt][r] += a1_lds[e][u] * wv;
                    else if (p == 2)  acc0[mt][r] += x_lds[e][u] * wv;
                    else {
                        acc3[mt][r][0] += x_lds[e][16 + u * 3 + 0] * wv;
                        acc3[mt][r][1] += x_lds[e][16 + u * 3 + 1] * wv;
                        acc3[mt][r][2] += x_lds[e][16 + u * 3 + 2] * wv;
                    }
                }
            }
    }

    #pragma unroll
    for (int mt = 0; mt < 2; ++mt)
        #pragma unroll
        for (int r = 0; r < 4; ++r) {
            int e = mt * 16 + 4 * g + r;
            if (p == 0)       r0_lds[e][v] = acc0[mt][r];
            else if (p == 1)  r1_lds[e][v] = acc0[mt][r];
            else if (p == 2)  r2_lds[e][v] = acc0[mt][r];
            else {
                r3_lds[e][v * 3 + 0] = acc3[mt][r][0];
                r3_lds[e][v * 3 + 1] = acc3[mt][r][1];
                r3_lds[e][v * 3 + 2] = acc3[mt][r][2];
            }
        }
    __syncthreads();   // r*_lds ready; also last reads of h_lds are done -> safe to alias

    // ---- phase D: combine per-edge outputs, run-merge by dst, reduced atomics ----
    float* vbuf = (float*)h_lds;   // 32 x 64 f32 = 8 KB, aliases h_lds (16 KB)
    {
        float scale = rsqrtf((float)nn[0]);
        const float pw0 = 0.17677669529663687f;          // sqrt(1/32); pw1/sqrt(3) == pw0
        float k0 = pw0 * scale;
        float k1 = k0 * 0.57735026918962576f;            // extra 1/sqrt(3) on path 1

        int e  = tid >> 3;
        int j0 = (tid & 7) * 8;
        float y0  = sh_lds[e][0];
        float y1x = sh_lds[e][1], y1y = sh_lds[e][2], y1z = sh_lds[e][3];
        #pragma unroll
        for (int jj = 0; jj < 8; ++jj) {
            int j = j0 + jj;
            float val;
            if (j < 16) {
                val = k0 * r0_lds[e][j] + k1 * r1_lds[e][j];
            } else {
                int t2 = j - 16;
                int vv = t2 / 3;
                int i  = t2 - vv * 3;
                float y1i = (i == 0) ? y1x : ((i == 1) ? y1y : y1z);
                val = k0 * (y1i * r2_lds[e][vv] + y0 * r3_lds[e][t2]);
            }
            vbuf[e * 64 + j] = val;
        }
    }
    if (tid < TE)
        head_lds[tid] = (tid == 0) || (dst_lds[tid] != dst_lds[tid - 1]);
    __syncthreads();
    {
        int e   = tid >> 3;
        int oct = tid & 7;
        if (head_lds[e]) {
            int L = 1;
            while (e + L < TE && !head_lds[e + L]) ++L;
            float4 s0 = *(const float4*)(vbuf + e * 64 + oct * 8);
            float4 s1 = *(const float4*)(vbuf + e * 64 + oct * 8 + 4);
            for (int i = 1; i < L; ++i) {
                const float4* q = (const float4*)(vbuf + (e + i) * 64 + oct * 8);
                float4 t0 = q[0], t1 = q[1];
                s0.x += t0.x; s0.y += t0.y; s0.z += t0.z; s0.w += t0.w;
                s1.x += t1.x; s1.y += t1.y; s1.z += t1.z; s1.w += t1.w;
            }
            float* op = outg + (size_t)dst_lds[e] * 64 + oct * 8;
            atomicAdd(op + 0, s0.x); atomicAdd(op + 1, s0.y);
            atomicAdd(op + 2, s0.z); atomicAdd(op + 3, s0.w);
            atomicAdd(op + 4, s1.x); atomicAdd(op + 5, s1.y);
            atomicAdd(op + 6, s1.z); atomicAdd(op + 7, s1.w);
        }
    }
}

extern "C" void kernel_launch(void* const* d_in, const int* in_sizes, int n_in,
                              void* d_out, int out_size, void* d_ws, size_t ws_size,
                              hipStream_t stream) {
    const int*   esrc  = (const int*)d_in[0];
    const int*   edst  = (const int*)d_in[1];
    const float* nodef = (const float*)d_in[2];
    const float* esh   = (const float*)d_in[3];
    const float* ellv  = (const float*)d_in[4];
    const float* w1    = (const float*)d_in[5];
    const float* w2    = (const float*)d_in[6];
    const int*   nn    = (const int*)d_in[7];
    float* outg = (float*)d_out;

    char* ws = (char*)d_ws;
    short* w2p    = (short*)ws;                        // 512 KiB
    int*   counts = (int*)(ws + (512 << 10));          // 40 KB
    int*   cursor = (int*)(ws + (512 << 10) + 65536);  // 40 KB
    int*   permv  = (int*)(ws + (512 << 10) + 131072); // 640 KB

    hipMemsetAsync(d_out, 0, (size_t)out_size * sizeof(float), stream);
    pack_w2<<<1024, 256, 0, stream>>>(w2, w2p);
    zero_counts<<<(N_NODES + 255) / 256, 256, 0, stream>>>(counts);
    hist_kernel<<<N_EDGES / 256, 256, 0, stream>>>(edst, counts);
    scan_kernel<<<1, 256, 0, stream>>>(counts, cursor);
    scatter_kernel<<<N_EDGES / 256, 256, 0, stream>>>(edst, cursor, permv);
    conv_kernel<<<N_EDGES / TE, 256, 0, stream>>>(permv, esrc, edst, nodef, esh, ellv,
                                                  w1, w2p, nn, outg);
}

// Round 5
// 341.748 us; speedup vs baseline: 1.2579x; 1.0051x over previous
//
#include <hip/hip_runtime.h>
#include <hip/hip_bf16.h>

#define N_NODES 10000
#define N_EDGES 160000
#define TE 32   // edges per block

typedef __attribute__((ext_vector_type(8))) short bfrag_t;   // 8 x bf16
typedef __attribute__((ext_vector_type(4))) float facc_t;    // 4 x f32

__device__ inline short f2bf(float f) {
    union { float f; unsigned u; } x; x.f = f;
    unsigned r = x.u + 0x7FFFu + ((x.u >> 16) & 1u);
    return (short)(r >> 16);
}

// Pack W2 (256x1024 f32, row-major) into MFMA B fragments, bf16, with 1/16 scale folded.
__global__ void pack_w2(const float* __restrict__ w2, short* __restrict__ outp) {
    int g = blockIdx.x * blockDim.x + threadIdx.x;  // 0..262143
    int j    = g & 7;
    int lane = (g >> 3) & 63;
    int k    = (g >> 9) & 7;
    int nt   = (g >> 12) & 15;
    int p    = g >> 16;
    int row = k * 32 + ((lane >> 4) << 3) + j;
    int col = p * 256 + nt * 16 + (lane & 15);
    outp[g] = f2bf(w2[row * 1024 + col] * 0.0625f);
}

// ---- dst-sort infrastructure ----
__global__ void zero_counts(int* __restrict__ counts) {
    int i = blockIdx.x * blockDim.x + threadIdx.x;
    if (i < N_NODES) counts[i] = 0;
}

__global__ void hist_kernel(const int* __restrict__ edst, int* __restrict__ counts) {
    int e = blockIdx.x * blockDim.x + threadIdx.x;
    if (e < N_EDGES) atomicAdd(&counts[edst[e]], 1);
}

__global__ __launch_bounds__(256) void scan_kernel(const int* __restrict__ counts,
                                                   int* __restrict__ cursor) {
    __shared__ int part[256];
    const int t = threadIdx.x;
    const int CH = 40;
    int base = t * CH;
    int s = 0;
    for (int i = 0; i < CH; ++i) {
        int idx = base + i;
        if (idx < N_NODES) s += counts[idx];
    }
    part[t] = s;
    __syncthreads();
    for (int off = 1; off < 256; off <<= 1) {
        int add = (t >= off) ? part[t - off] : 0;
        __syncthreads();
        part[t] += add;
        __syncthreads();
    }
    int run = part[t] - s;
    for (int i = 0; i < CH; ++i) {
        int idx = base + i;
        if (idx < N_NODES) {
            cursor[idx] = run;
            run += counts[idx];
        }
    }
}

__global__ void scatter_kernel(const int* __restrict__ edst, int* __restrict__ cursor,
                               int* __restrict__ perm) {
    int e = blockIdx.x * blockDim.x + threadIdx.x;
    if (e < N_EDGES) {
        int pos = atomicAdd(&cursor[edst[e]], 1);
        perm[pos] = e;
    }
}

__global__ __launch_bounds__(256) void conv_kernel(
    const int* __restrict__ perm,
    const int* __restrict__ esrc, const int* __restrict__ edst,
    const float* __restrict__ nodef, const float* __restrict__ esh,
    const float* __restrict__ ell, const float* __restrict__ w1,
    const short* __restrict__ w2p, const int* __restrict__ nn,
    float* __restrict__ outg)
{
    // hbuf: h (bf16, swizzled) during phases B/C; r0..r3 (f32) after the post-C barrier
    __shared__ __align__(16) char hbuf[TE * 512];               // 16 KB
    short* h_lds  = (short*)hbuf;
    float* r0_lds = (float*)hbuf;                               // [TE][17] flat, 2176 B
    float* r1_lds = (float*)(hbuf + 2176);                      // [TE][17]
    float* r2_lds = (float*)(hbuf + 4352);                      // [TE][17]
    float* r3_lds = (float*)(hbuf + 6528);                      // [TE][49], ends 12800
    // x_lds during phases B/C; vbuf (32x64 f32 = 8 KB) during phase D
    __shared__ __align__(16) float x_lds[TE][68];               // 8704 B
    float* vbuf = (float*)x_lds;
    __shared__ float a0_lds[TE][17];   // s0*y0
    __shared__ float a1_lds[TE][17];   // sum_i v1[u][i]*y1[i]
    __shared__ float sh_lds[TE][4];
    __shared__ float el_lds[TE][3];
    __shared__ int   src_lds[TE];
    __shared__ int   dst_lds[TE];
    __shared__ int   head_lds[TE];

    const int tid = threadIdx.x;
    const int e0  = blockIdx.x * TE;

    // ---- phase A: gathered edge-wise loads (via perm) ----
    if (tid < TE) {
        int pe = perm[e0 + tid];
        src_lds[tid] = esrc[pe];
        dst_lds[tid] = edst[pe];
        float4 s4 = *(const float4*)(esh + (size_t)pe * 4);
        sh_lds[tid][0] = s4.x; sh_lds[tid][1] = s4.y;
        sh_lds[tid][2] = s4.z; sh_lds[tid][3] = s4.w;
        const float* lp = ell + (size_t)pe * 3;
        el_lds[tid][0] = lp[0]; el_lds[tid][1] = lp[1]; el_lds[tid][2] = lp[2];
    }
    __syncthreads();

    // ---- phase B: x gather, h compute (to LDS bf16), coefficient precompute ----
    {
        int e = tid >> 3, part = tid & 7;
        int s = src_lds[e];
        const float4* sp = (const float4*)(nodef + (size_t)s * 64 + part * 8);
        float4 u0 = sp[0], u1 = sp[1];
        float* xr = &x_lds[e][part * 8];
        *(float4*)(xr)     = u0;
        *(float4*)(xr + 4) = u1;
    }
    {
        int e = tid >> 3, c0 = (tid & 7) * 32;
        float l0 = el_lds[e][0], l1 = el_lds[e][1], l2 = el_lds[e][2];
        #pragma unroll
        for (int s = 0; s < 4; ++s) {
            bfrag_t hv;
            #pragma unroll
            for (int m = 0; m < 8; ++m) {
                int c = c0 + s * 8 + m;
                float a = l0 * w1[c] + l1 * w1[256 + c] + l2 * w1[512 + c];
                a = fmaxf(a, 0.f) * 0.8164965809277260f;  // sqrt(2/3), relu scale folded
                hv[m] = f2bf(a);
            }
            int byte = (e * 512 + (c0 + s * 8) * 2) ^ ((e & 7) << 4);
            *(bfrag_t*)((char*)h_lds + byte) = hv;
        }
    }
    __syncthreads();
    {
        #pragma unroll
        for (int q = tid; q < TE * 16; q += 256) {
            int e = q >> 4, u = q & 15;
            float y0 = sh_lds[e][0];
            a0_lds[e][u] = x_lds[e][u] * y0;
            a1_lds[e][u] = x_lds[e][16 + u * 3 + 0] * sh_lds[e][1]
                         + x_lds[e][16 + u * 3 + 1] * sh_lds[e][2]
                         + x_lds[e][16 + u * 3 + 2] * sh_lds[e][3];
        }
    }
    __syncthreads();

    // ---- phase C: MFMA GEMM (wave p == TP path p) fused with TP reduction ----
    const int lane = tid & 63;
    const int p    = tid >> 6;
    const int g    = lane >> 4;
    const int v    = lane & 15;

    float acc0[2][4];
    float acc3[2][4][3];
    #pragma unroll
    for (int mt = 0; mt < 2; ++mt)
        #pragma unroll
        for (int r = 0; r < 4; ++r) {
            acc0[mt][r] = 0.f;
            acc3[mt][r][0] = 0.f; acc3[mt][r][1] = 0.f; acc3[mt][r][2] = 0.f;
        }

    const bfrag_t* Bp = (const bfrag_t*)w2p + (size_t)(p * 128) * 64 + lane;

    const int rb0 = v * 512;
    const int rb1 = (16 + v) * 512;
    const int swz = (v & 7) << 4;

    #pragma unroll
    for (int ntc = 0; ntc < 4; ++ntc) {
        facc_t acc[2][4];
        #pragma unroll
        for (int mt = 0; mt < 2; ++mt)
            #pragma unroll
            for (int q = 0; q < 4; ++q)
                acc[mt][q] = (facc_t){0.f, 0.f, 0.f, 0.f};

        #pragma unroll
        for (int k = 0; k < 8; ++k) {
            int koff = (k * 32 + 8 * g) * 2;
            bfrag_t a0 = *(const bfrag_t*)((const char*)h_lds + ((rb0 + koff) ^ swz));
            bfrag_t a1 = *(const bfrag_t*)((const char*)h_lds + ((rb1 + koff) ^ swz));
            #pragma unroll
            for (int q = 0; q < 4; ++q) {
                int nt = ntc * 4 + q;
                bfrag_t b = Bp[(size_t)(nt * 8 + k) * 64];
                acc[0][q] = __builtin_amdgcn_mfma_f32_16x16x32_bf16(a0, b, acc[0][q], 0, 0, 0);
                acc[1][q] = __builtin_amdgcn_mfma_f32_16x16x32_bf16(a1, b, acc[1][q], 0, 0, 0);
            }
        }
        #pragma unroll
        for (int mt = 0; mt < 2; ++mt)
            #pragma unroll
            for (int r = 0; r < 4; ++r) {
                int e = mt * 16 + 4 * g + r;
                #pragma unroll
                for (int q = 0; q < 4; ++q) {
                    int u = ntc * 4 + q;
                    float wv = acc[mt][q][r];
                    if (p == 0)       acc0[mt][r] += a0_lds[e][u] * wv;
                    else if (p == 1)  acc0[mt][r] += a1_lds[e][u] * wv;
                    else if (p == 2)  acc0[mt][r] += x_lds[e][u] * wv;
                    else {
                        acc3[mt][r][0] += x_lds[e][16 + u * 3 + 0] * wv;
                        acc3[mt][r][1] += x_lds[e][16 + u * 3 + 1] * wv;
                        acc3[mt][r][2] += x_lds[e][16 + u * 3 + 2] * wv;
                    }
                }
            }
    }

    __syncthreads();   // ALL h_lds reads complete -> safe to store r* into hbuf

    #pragma unroll
    for (int mt = 0; mt < 2; ++mt)
        #pragma unroll
        for (int r = 0; r < 4; ++r) {
            int e = mt * 16 + 4 * g + r;
            if (p == 0)       r0_lds[e * 17 + v] = acc0[mt][r];
            else if (p == 1)  r1_lds[e * 17 + v] = acc0[mt][r];
            else if (p == 2)  r2_lds[e * 17 + v] = acc0[mt][r];
            else {
                r3_lds[e * 49 + v * 3 + 0] = acc3[mt][r][0];
                r3_lds[e * 49 + v * 3 + 1] = acc3[mt][r][1];
                r3_lds[e * 49 + v * 3 + 2] = acc3[mt][r][2];
            }
        }
    __syncthreads();   // r* ready; also all x_lds/a*_lds reads done -> vbuf may alias x_lds

    // ---- phase D: combine per-edge outputs, run-merge by dst, reduced atomics ----
    {
        float scale = rsqrtf((float)nn[0]);
        const float pw0 = 0.17677669529663687f;          // sqrt(1/32); pw1/sqrt(3) == pw0
        float k0 = pw0 * scale;
        float k1 = k0 * 0.57735026918962576f;            // extra 1/sqrt(3) on path 1

        int e  = tid >> 3;
        int j0 = (tid & 7) * 8;
        float y0  = sh_lds[e][0];
        float y1x = sh_lds[e][1], y1y = sh_lds[e][2], y1z = sh_lds[e][3];
        #pragma unroll
        for (int jj = 0; jj < 8; ++jj) {
            int j = j0 + jj;
            float val;
            if (j < 16) {
                val = k0 * r0_lds[e * 17 + j] + k1 * r1_lds[e * 17 + j];
            } else {
                int t2 = j - 16;
                int vv = t2 / 3;
                int i  = t2 - vv * 3;
                float y1i = (i == 0) ? y1x : ((i == 1) ? y1y : y1z);
                val = k0 * (y1i * r2_lds[e * 17 + vv] + y0 * r3_lds[e * 49 + t2]);
            }
            vbuf[e * 64 + j] = val;
        }
    }
    if (tid < TE)
        head_lds[tid] = (tid == 0) || (dst_lds[tid] != dst_lds[tid - 1]);
    __syncthreads();
    {
        int e   = tid >> 3;
        int oct = tid & 7;
        if (head_lds[e]) {
            int L = 1;
            while (e + L < TE && !head_lds[e + L]) ++L;
            float4 s0 = *(const float4*)(vbuf + e * 64 + oct * 8);
            float4 s1 = *(const float4*)(vbuf + e * 64 + oct * 8 + 4);
            for (int i = 1; i < L; ++i) {
                const float4* q = (const float4*)(vbuf + (e + i) * 64 + oct * 8);
                float4 t0 = q[0], t1 = q[1];
                s0.x += t0.x; s0.y += t0.y; s0.z += t0.z; s0.w += t0.w;
                s1.x += t1.x; s1.y += t1.y; s1.z += t1.z; s1.w += t1.w;
            }
            float* op = outg + (size_t)dst_lds[e] * 64 + oct * 8;
            atomicAdd(op + 0, s0.x); atomicAdd(op + 1, s0.y);
            atomicAdd(op + 2, s0.z); atomicAdd(op + 3, s0.w);
            atomicAdd(op + 4, s1.x); atomicAdd(op + 5, s1.y);
            atomicAdd(op + 6, s1.z); atomicAdd(op + 7, s1.w);
        }
    }
}

extern "C" void kernel_launch(void* const* d_in, const int* in_sizes, int n_in,
                              void* d_out, int out_size, void* d_ws, size_t ws_size,
                              hipStream_t stream) {
    const int*   esrc  = (const int*)d_in[0];
    const int*   edst  = (const int*)d_in[1];
    const float* nodef = (const float*)d_in[2];
    const float* esh   = (const float*)d_in[3];
    const float* ellv  = (const float*)d_in[4];
    const float* w1    = (const float*)d_in[5];
    const float* w2    = (const float*)d_in[6];
    const int*   nn    = (const int*)d_in[7];
    float* outg = (float*)d_out;

    char* ws = (char*)d_ws;
    short* w2p    = (short*)ws;                        // 512 KiB
    int*   counts = (int*)(ws + (512 << 10));          // 40 KB
    int*   cursor = (int*)(ws + (512 << 10) + 65536);  // 40 KB
    int*   permv  = (int*)(ws + (512 << 10) + 131072); // 640 KB

    hipMemsetAsync(d_out, 0, (size_t)out_size * sizeof(float), stream);
    pack_w2<<<1024, 256, 0, stream>>>(w2, w2p);
    zero_counts<<<(N_NODES + 255) / 256, 256, 0, stream>>>(counts);
    hist_kernel<<<N_EDGES / 256, 256, 0, stream>>>(edst, counts);
    scan_kernel<<<1, 256, 0, stream>>>(counts, cursor);
    scatter_kernel<<<N_EDGES / 256, 256, 0, stream>>>(edst, cursor, permv);
    conv_kernel<<<N_EDGES / TE, 256, 0, stream>>>(permv, esrc, edst, nodef, esh, ellv,
                                                  w1, w2p, nn, outg);
}